// Round 2
// baseline (194.184 us; speedup 1.0000x reference)
//
#include <hip/hip_runtime.h>

#define NV 1084
#define BPB 8   // batches per verts block

// ws layout (floats):
//  [0, B*192)         A_rel [B][16][12]
//  [B*192, +1344)     M     [21][16][4]
//  next 48            Jt    [16][3]

__device__ inline void rodrigues9(float x, float y, float z, float R[9]) {
    float n2 = x * x + y * y + z * z + 1e-8f;
    float angle = sqrtf(n2);
    float inv = 1.0f / angle;
    float ax = x * inv, ay = y * inv, az = z * inv;
    float c = cosf(angle), s = sinf(angle);
    float C = 1.0f - c;
    R[0] = 1.0f - C * (ay * ay + az * az);
    R[1] = -s * az + C * ax * ay;
    R[2] = s * ay + C * ax * az;
    R[3] = s * az + C * ax * ay;
    R[4] = 1.0f - C * (ax * ax + az * az);
    R[5] = -s * ax + C * ay * az;
    R[6] = -s * ay + C * ax * az;
    R[7] = s * ax + C * ay * az;
    R[8] = 1.0f - C * (ax * ax + ay * ay);
}

// Batch-independent reductions over vertices: M[21][16][4] and Jt[16][3].
__global__ __launch_bounds__(384) void precompute_kernel(
    const float* __restrict__ vt, const float* __restrict__ jreg,
    const float* __restrict__ wts, float* __restrict__ Mbuf, float* __restrict__ jt) {
    int t = threadIdx.x;
    int v0 = blockIdx.x * 17;
    int v1 = min(v0 + 17, NV);
    if (t < 336) {
        int j = t >> 4, k = t & 15;
        float m0 = 0.f, m1 = 0.f, m2 = 0.f, s = 0.f;
        for (int v = v0; v < v1; ++v) {
            float jw = jreg[v * 21 + j] * wts[v * 16 + k];
            m0 += jw * vt[v * 3 + 0];
            m1 += jw * vt[v * 3 + 1];
            m2 += jw * vt[v * 3 + 2];
            s += jw;
        }
        float* mp = Mbuf + (t << 2);
        atomicAdd(mp + 0, m0);
        atomicAdd(mp + 1, m1);
        atomicAdd(mp + 2, m2);
        atomicAdd(mp + 3, s);
    } else if (t < 336 + 48) {
        int o = t - 336;
        int j = o / 3, c = o % 3;  // j < 16
        float acc = 0.f;
        for (int v = v0; v < v1; ++v) acc += vt[v * 3 + c] * jreg[v * 21 + j];
        atomicAdd(&jt[o], acc);
    }
}

// FK with euler fused: one thread per batch. Writes A_rel[b][16][12].
__global__ __launch_bounds__(64) void fk_kernel(
    const float* __restrict__ theta, const float* __restrict__ wrist,
    const float* __restrict__ hc, const float* __restrict__ hm,
    const float* __restrict__ jt, float* __restrict__ wsA) {
    __shared__ float sj[48];
    int t = threadIdx.x;
    if (t < 48) sj[t] = jt[t];
    __syncthreads();
    int b = blockIdx.x * 64 + t;

    // euler_pose for this batch (45 values), theta cached in regs
    float th[45];
    const float* tb = theta + (size_t)b * 45;
#pragma unroll
    for (int k = 0; k < 45; ++k) th[k] = tb[k];
    float e[45];
#pragma unroll
    for (int col = 0; col < 45; ++col) {
        float acc = hm[col];
#pragma unroll
        for (int k = 0; k < 45; ++k) acc += th[k] * hc[k * 45 + col];
        e[col] = acc;
    }

    float R[9];
    rodrigues9(wrist[b * 3 + 0], wrist[b * 3 + 1], wrist[b * 3 + 2], R);
    float J0x = sj[0], J0y = sj[1], J0z = sj[2];
    float A0[12];
    A0[0] = R[0]; A0[1] = R[1]; A0[2] = R[2]; A0[3] = J0x;
    A0[4] = R[3]; A0[5] = R[4]; A0[6] = R[5]; A0[7] = J0y;
    A0[8] = R[6]; A0[9] = R[7]; A0[10] = R[8]; A0[11] = J0z;
    float* out = wsA + (size_t)b * 192;
#pragma unroll
    for (int r = 0; r < 3; ++r) {
        out[r * 4 + 0] = A0[r * 4 + 0];
        out[r * 4 + 1] = A0[r * 4 + 1];
        out[r * 4 + 2] = A0[r * 4 + 2];
        out[r * 4 + 3] = A0[r * 4 + 3] -
            (A0[r * 4 + 0] * J0x + A0[r * 4 + 1] * J0y + A0[r * 4 + 2] * J0z);
    }
#pragma unroll
    for (int chain = 0; chain < 5; ++chain) {
        float Ap[12];
#pragma unroll
        for (int q = 0; q < 12; ++q) Ap[q] = A0[q];
        int p = 0;
#pragma unroll
        for (int step = 0; step < 3; ++step) {
            int i = chain * 3 + step + 1;
            int cb = 3 * (i - 1);
            rodrigues9(e[cb + 0], e[cb + 1], e[cb + 2], R);
            float tx = sj[i * 3 + 0] - sj[p * 3 + 0];
            float ty = sj[i * 3 + 1] - sj[p * 3 + 1];
            float tz = sj[i * 3 + 2] - sj[p * 3 + 2];
            float An[12];
#pragma unroll
            for (int r = 0; r < 3; ++r) {
                An[r * 4 + 0] = Ap[r * 4 + 0] * R[0] + Ap[r * 4 + 1] * R[3] + Ap[r * 4 + 2] * R[6];
                An[r * 4 + 1] = Ap[r * 4 + 0] * R[1] + Ap[r * 4 + 1] * R[4] + Ap[r * 4 + 2] * R[7];
                An[r * 4 + 2] = Ap[r * 4 + 0] * R[2] + Ap[r * 4 + 1] * R[5] + Ap[r * 4 + 2] * R[8];
                An[r * 4 + 3] = Ap[r * 4 + 3] + Ap[r * 4 + 0] * tx + Ap[r * 4 + 1] * ty + Ap[r * 4 + 2] * tz;
            }
            float jx = sj[i * 3 + 0], jy = sj[i * 3 + 1], jz = sj[i * 3 + 2];
            float* oi = out + i * 12;
#pragma unroll
            for (int r = 0; r < 3; ++r) {
                oi[r * 4 + 0] = An[r * 4 + 0];
                oi[r * 4 + 1] = An[r * 4 + 1];
                oi[r * 4 + 2] = An[r * 4 + 2];
                oi[r * 4 + 3] = An[r * 4 + 3] -
                    (An[r * 4 + 0] * jx + An[r * 4 + 1] * jy + An[r * 4 + 2] * jz);
            }
#pragma unroll
            for (int q = 0; q < 12; ++q) Ap[q] = An[q];
            p = i;
        }
    }
}

#define FMA12(Ti, wk)                                                     \
    Ti[0] += wk * a0.x; Ti[1] += wk * a0.y; Ti[2] += wk * a0.z;           \
    Ti[3] += wk * a0.w; Ti[4] += wk * a1.x; Ti[5] += wk * a1.y;           \
    Ti[6] += wk * a1.z; Ti[7] += wk * a1.w; Ti[8] += wk * a2.x;           \
    Ti[9] += wk * a2.y; Ti[10] += wk * a2.z; Ti[11] += wk * a2.w;

#define SET12(Ti, wk)                                                     \
    Ti[0] = wk * a0.x; Ti[1] = wk * a0.y; Ti[2] = wk * a0.z;              \
    Ti[3] = wk * a0.w; Ti[4] = wk * a1.x; Ti[5] = wk * a1.y;              \
    Ti[6] = wk * a1.z; Ti[7] = wk * a1.w; Ti[8] = wk * a2.x;              \
    Ti[9] = wk * a2.y; Ti[10] = wk * a2.z; Ti[11] = wk * a2.w;

template <int VPT>
__device__ inline void blend_verts(const float* sA, const float* __restrict__ wts,
                                   const float* __restrict__ vtpl,
                                   float* __restrict__ verts, int bg, int vbase, int t) {
    float w[VPT][16], vx[VPT], vy[VPT], vz[VPT];
    bool val[VPT];
#pragma unroll
    for (int i = 0; i < VPT; ++i) {
        int v = vbase + i * 256 + t;
        val[i] = (v < NV);
        if (val[i]) {
            const float4* wp = (const float4*)&wts[v * 16];
            float4 q0 = wp[0], q1 = wp[1], q2 = wp[2], q3 = wp[3];
            w[i][0] = q0.x; w[i][1] = q0.y; w[i][2] = q0.z; w[i][3] = q0.w;
            w[i][4] = q1.x; w[i][5] = q1.y; w[i][6] = q1.z; w[i][7] = q1.w;
            w[i][8] = q2.x; w[i][9] = q2.y; w[i][10] = q2.z; w[i][11] = q2.w;
            w[i][12] = q3.x; w[i][13] = q3.y; w[i][14] = q3.z; w[i][15] = q3.w;
            vx[i] = vtpl[v * 3 + 0]; vy[i] = vtpl[v * 3 + 1]; vz[i] = vtpl[v * 3 + 2];
        } else {
#pragma unroll
            for (int q = 0; q < 16; ++q) w[i][q] = 0.f;
            vx[i] = vy[i] = vz[i] = 0.f;
        }
    }
#pragma unroll 1
    for (int bb = 0; bb < BPB; ++bb) {
        const float* A = &sA[bb * 192];
        float T[VPT][12];
        float4 a0 = *(const float4*)&A[0];
        float4 a1 = *(const float4*)&A[4];
        float4 a2 = *(const float4*)&A[8];
#pragma unroll
        for (int i = 0; i < VPT; ++i) {
            float wk = w[i][0];
            SET12(T[i], wk)
        }
#pragma unroll
        for (int k = 1; k < 16; ++k) {
            a0 = *(const float4*)&A[k * 12 + 0];
            a1 = *(const float4*)&A[k * 12 + 4];
            a2 = *(const float4*)&A[k * 12 + 8];
#pragma unroll
            for (int i = 0; i < VPT; ++i) {
                float wk = w[i][k];
                FMA12(T[i], wk)
            }
        }
        int b = bg * BPB + bb;
#pragma unroll
        for (int i = 0; i < VPT; ++i) {
            if (val[i]) {
                float ox = T[i][0] * vx[i] + T[i][1] * vy[i] + T[i][2] * vz[i] + T[i][3];
                float oy = T[i][4] * vx[i] + T[i][5] * vy[i] + T[i][6] * vz[i] + T[i][7];
                float oz = T[i][8] * vx[i] + T[i][9] * vy[i] + T[i][10] * vz[i] + T[i][11];
                float* o = verts + (size_t)b * (NV * 3) + (vbase + i * 256 + t) * 3;
                o[0] = ox; o[1] = oy; o[2] = oz;
            }
        }
    }
}

// grid = nbg*2. Even blocks: 1024 verts (VPT=4). Odd blocks: 60-vert tail + joints.
__global__ __launch_bounds__(256) void verts_joints_kernel(
    const float* __restrict__ wsA, const float* __restrict__ Mbuf,
    const float* __restrict__ wts, const float* __restrict__ vtpl,
    float* __restrict__ verts, float* __restrict__ jout) {
    __shared__ float sA[BPB * 192];
    __shared__ float sM[1344];
    int bid = blockIdx.x;
    int bg = bid >> 1, chunk = bid & 1;
    int t = threadIdx.x;
    const float* src = wsA + (size_t)bg * (BPB * 192);
    for (int q = t; q < BPB * 192; q += 256) sA[q] = src[q];
    if (chunk) {
        for (int q = t; q < 1344; q += 256) sM[q] = Mbuf[q];
    }
    __syncthreads();

    if (chunk == 0) {
        blend_verts<4>(sA, wts, vtpl, verts, bg, 0, t);
    } else {
        blend_verts<1>(sA, wts, vtpl, verts, bg, 1024, t);
        // joints: jout[b, j, c] = sum_k sum_d M[j][k][d] * A[b][k][c*4+d]
        for (int o = t; o < BPB * 63; o += 256) {
            int bl = o / 63;
            int rem = o - bl * 63;
            int j = rem / 3;
            int c = rem - j * 3;
            const float* A = &sA[bl * 192 + c * 4];
            const float* Mj = &sM[j * 64];
            float acc = 0.f;
#pragma unroll
            for (int k = 0; k < 16; ++k) {
                float4 a = *(const float4*)&A[k * 12];
                float4 m = *(const float4*)&Mj[k * 4];
                acc += a.x * m.x + a.y * m.y + a.z * m.z + a.w * m.w;
            }
            jout[(size_t)(bg * BPB + bl) * 63 + rem] = acc;
        }
    }
}

extern "C" void kernel_launch(void* const* d_in, const int* in_sizes, int n_in,
                              void* d_out, int out_size, void* d_ws, size_t ws_size,
                              hipStream_t stream) {
    const float* theta = (const float*)d_in[1];
    const float* wrist = (const float*)d_in[2];
    const float* vtpl  = (const float*)d_in[3];
    const float* jreg  = (const float*)d_in[4];
    const float* hc    = (const float*)d_in[5];
    const float* hm    = (const float*)d_in[6];
    const float* wts   = (const float*)d_in[7];
    int B = in_sizes[1] / 45;  // 4096

    float* ws   = (float*)d_ws;
    float* wsA  = ws;                     // B*192
    float* Mbuf = ws + (size_t)B * 192;   // 1344
    float* jt   = Mbuf + 1344;            // 48
    float* verts = (float*)d_out;
    float* jout  = verts + (size_t)B * NV * 3;

    hipMemsetAsync(Mbuf, 0, (1344 + 48) * sizeof(float), stream);
    precompute_kernel<<<64, 384, 0, stream>>>(vtpl, jreg, wts, Mbuf, jt);
    fk_kernel<<<B / 64, 64, 0, stream>>>(theta, wrist, hc, hm, jt, wsA);
    int nbg = B / BPB;
    verts_joints_kernel<<<nbg * 2, 256, 0, stream>>>(wsA, Mbuf, wts, vtpl, verts, jout);
}

// Round 3
// 120.619 us; speedup vs baseline: 1.6099x; 1.6099x over previous
//
#include <hip/hip_runtime.h>

#define NV 1084
#define BPB 8   // batches per verts block

// ws layout (floats):
//  [0, B*192)         A_rel [B][16][12]
//  [B*192, +1344)     M     [21][16][4]
//  next 48            Jt    [16][3]
//  next B*45          euler_pose [B][45]

__device__ inline void rodrigues9(float x, float y, float z, float R[9]) {
    float n2 = x * x + y * y + z * z + 1e-8f;
    float angle = sqrtf(n2);
    float inv = 1.0f / angle;
    float ax = x * inv, ay = y * inv, az = z * inv;
    float c = cosf(angle), s = sinf(angle);
    float C = 1.0f - c;
    R[0] = 1.0f - C * (ay * ay + az * az);
    R[1] = -s * az + C * ax * ay;
    R[2] = s * ay + C * ax * az;
    R[3] = s * az + C * ax * ay;
    R[4] = 1.0f - C * (ax * ax + az * az);
    R[5] = -s * ax + C * ay * az;
    R[6] = -s * ay + C * ax * az;
    R[7] = s * ax + C * ay * az;
    R[8] = 1.0f - C * (ax * ax + ay * ay);
}

// Batch-independent reductions over vertices: M[21][16][4] and Jt[16][3].
__global__ __launch_bounds__(384) void precompute_kernel(
    const float* __restrict__ vt, const float* __restrict__ jreg,
    const float* __restrict__ wts, float* __restrict__ Mbuf, float* __restrict__ jt) {
    int t = threadIdx.x;
    int v0 = blockIdx.x * 17;
    int v1 = min(v0 + 17, NV);
    if (t < 336) {
        int j = t >> 4, k = t & 15;
        float m0 = 0.f, m1 = 0.f, m2 = 0.f, s = 0.f;
        for (int v = v0; v < v1; ++v) {
            float jw = jreg[v * 21 + j] * wts[v * 16 + k];
            m0 += jw * vt[v * 3 + 0];
            m1 += jw * vt[v * 3 + 1];
            m2 += jw * vt[v * 3 + 2];
            s += jw;
        }
        float* mp = Mbuf + (t << 2);
        atomicAdd(mp + 0, m0);
        atomicAdd(mp + 1, m1);
        atomicAdd(mp + 2, m2);
        atomicAdd(mp + 3, s);
    } else if (t < 336 + 48) {
        int o = t - 336;
        int j = o / 3, c = o % 3;  // j < 16
        float acc = 0.f;
        for (int v = v0; v < v1; ++v) acc += vt[v * 3 + c] * jreg[v * 21 + j];
        atomicAdd(&jt[o], acc);
    }
}

// euler_pose[b,col] = hm[col] + sum_k theta[b,k] * hc[k,col]
__global__ __launch_bounds__(256) void euler_kernel(
    const float* __restrict__ theta, const float* __restrict__ hc,
    const float* __restrict__ hm, float* __restrict__ out, int total) {
    int i = blockIdx.x * 256 + threadIdx.x;
    if (i >= total) return;
    int b = i / 45, col = i % 45;
    const float* th = theta + b * 45;
    float acc = hm[col];
#pragma unroll
    for (int k = 0; k < 45; ++k) acc += th[k] * hc[k * 45 + col];
    out[i] = acc;
}

// Forward kinematics: one thread per batch. Writes A_rel[b][16][12].
__global__ __launch_bounds__(64) void fk_kernel(
    const float* __restrict__ wrist, const float* __restrict__ euler,
    const float* __restrict__ jt, float* __restrict__ wsA) {
    __shared__ float sj[48];
    int t = threadIdx.x;
    if (t < 48) sj[t] = jt[t];
    __syncthreads();
    int b = blockIdx.x * 64 + t;
    float R[9];
    rodrigues9(wrist[b * 3 + 0], wrist[b * 3 + 1], wrist[b * 3 + 2], R);
    float J0x = sj[0], J0y = sj[1], J0z = sj[2];
    float A0[12];
    A0[0] = R[0]; A0[1] = R[1]; A0[2] = R[2]; A0[3] = J0x;
    A0[4] = R[3]; A0[5] = R[4]; A0[6] = R[5]; A0[7] = J0y;
    A0[8] = R[6]; A0[9] = R[7]; A0[10] = R[8]; A0[11] = J0z;
    float* out = wsA + (size_t)b * 192;
#pragma unroll
    for (int r = 0; r < 3; ++r) {
        out[r * 4 + 0] = A0[r * 4 + 0];
        out[r * 4 + 1] = A0[r * 4 + 1];
        out[r * 4 + 2] = A0[r * 4 + 2];
        out[r * 4 + 3] = A0[r * 4 + 3] -
            (A0[r * 4 + 0] * J0x + A0[r * 4 + 1] * J0y + A0[r * 4 + 2] * J0z);
    }
    const float* eb = euler + (size_t)b * 45;
#pragma unroll
    for (int chain = 0; chain < 5; ++chain) {
        float Ap[12];
#pragma unroll
        for (int q = 0; q < 12; ++q) Ap[q] = A0[q];
        int p = 0;
#pragma unroll
        for (int step = 0; step < 3; ++step) {
            int i = chain * 3 + step + 1;
            int cb = 3 * (i - 1);
            rodrigues9(eb[cb + 0], eb[cb + 1], eb[cb + 2], R);
            float tx = sj[i * 3 + 0] - sj[p * 3 + 0];
            float ty = sj[i * 3 + 1] - sj[p * 3 + 1];
            float tz = sj[i * 3 + 2] - sj[p * 3 + 2];
            float An[12];
#pragma unroll
            for (int r = 0; r < 3; ++r) {
                An[r * 4 + 0] = Ap[r * 4 + 0] * R[0] + Ap[r * 4 + 1] * R[3] + Ap[r * 4 + 2] * R[6];
                An[r * 4 + 1] = Ap[r * 4 + 0] * R[1] + Ap[r * 4 + 1] * R[4] + Ap[r * 4 + 2] * R[7];
                An[r * 4 + 2] = Ap[r * 4 + 0] * R[2] + Ap[r * 4 + 1] * R[5] + Ap[r * 4 + 2] * R[8];
                An[r * 4 + 3] = Ap[r * 4 + 3] + Ap[r * 4 + 0] * tx + Ap[r * 4 + 1] * ty + Ap[r * 4 + 2] * tz;
            }
            float jx = sj[i * 3 + 0], jy = sj[i * 3 + 1], jz = sj[i * 3 + 2];
            float* oi = out + i * 12;
#pragma unroll
            for (int r = 0; r < 3; ++r) {
                oi[r * 4 + 0] = An[r * 4 + 0];
                oi[r * 4 + 1] = An[r * 4 + 1];
                oi[r * 4 + 2] = An[r * 4 + 2];
                oi[r * 4 + 3] = An[r * 4 + 3] -
                    (An[r * 4 + 0] * jx + An[r * 4 + 1] * jy + An[r * 4 + 2] * jz);
            }
#pragma unroll
            for (int q = 0; q < 12; ++q) Ap[q] = An[q];
            p = i;
        }
    }
}

#define FMA12(Ti, wk)                                                     \
    Ti[0] += wk * a0.x; Ti[1] += wk * a0.y; Ti[2] += wk * a0.z;           \
    Ti[3] += wk * a0.w; Ti[4] += wk * a1.x; Ti[5] += wk * a1.y;           \
    Ti[6] += wk * a1.z; Ti[7] += wk * a1.w; Ti[8] += wk * a2.x;           \
    Ti[9] += wk * a2.y; Ti[10] += wk * a2.z; Ti[11] += wk * a2.w;

#define SET12(Ti, wk)                                                     \
    Ti[0] = wk * a0.x; Ti[1] = wk * a0.y; Ti[2] = wk * a0.z;              \
    Ti[3] = wk * a0.w; Ti[4] = wk * a1.x; Ti[5] = wk * a1.y;              \
    Ti[6] = wk * a1.z; Ti[7] = wk * a1.w; Ti[8] = wk * a2.x;              \
    Ti[9] = wk * a2.y; Ti[10] = wk * a2.z; Ti[11] = wk * a2.w;

template <int VPT>
__device__ inline void blend_verts(const float* sA, const float* __restrict__ wts,
                                   const float* __restrict__ vtpl,
                                   float* __restrict__ verts, int bg, int vbase, int t) {
    float w[VPT][16], vx[VPT], vy[VPT], vz[VPT];
    bool val[VPT];
#pragma unroll
    for (int i = 0; i < VPT; ++i) {
        int v = vbase + i * 256 + t;
        val[i] = (v < NV);
        if (val[i]) {
            const float4* wp = (const float4*)&wts[v * 16];
            float4 q0 = wp[0], q1 = wp[1], q2 = wp[2], q3 = wp[3];
            w[i][0] = q0.x; w[i][1] = q0.y; w[i][2] = q0.z; w[i][3] = q0.w;
            w[i][4] = q1.x; w[i][5] = q1.y; w[i][6] = q1.z; w[i][7] = q1.w;
            w[i][8] = q2.x; w[i][9] = q2.y; w[i][10] = q2.z; w[i][11] = q2.w;
            w[i][12] = q3.x; w[i][13] = q3.y; w[i][14] = q3.z; w[i][15] = q3.w;
            vx[i] = vtpl[v * 3 + 0]; vy[i] = vtpl[v * 3 + 1]; vz[i] = vtpl[v * 3 + 2];
        } else {
#pragma unroll
            for (int q = 0; q < 16; ++q) w[i][q] = 0.f;
            vx[i] = vy[i] = vz[i] = 0.f;
        }
    }
#pragma unroll 1
    for (int bb = 0; bb < BPB; ++bb) {
        const float* A = &sA[bb * 192];
        float T[VPT][12];
        float4 a0 = *(const float4*)&A[0];
        float4 a1 = *(const float4*)&A[4];
        float4 a2 = *(const float4*)&A[8];
#pragma unroll
        for (int i = 0; i < VPT; ++i) {
            float wk = w[i][0];
            SET12(T[i], wk)
        }
#pragma unroll
        for (int k = 1; k < 16; ++k) {
            a0 = *(const float4*)&A[k * 12 + 0];
            a1 = *(const float4*)&A[k * 12 + 4];
            a2 = *(const float4*)&A[k * 12 + 8];
#pragma unroll
            for (int i = 0; i < VPT; ++i) {
                float wk = w[i][k];
                FMA12(T[i], wk)
            }
        }
        int b = bg * BPB + bb;
#pragma unroll
        for (int i = 0; i < VPT; ++i) {
            if (val[i]) {
                float ox = T[i][0] * vx[i] + T[i][1] * vy[i] + T[i][2] * vz[i] + T[i][3];
                float oy = T[i][4] * vx[i] + T[i][5] * vy[i] + T[i][6] * vz[i] + T[i][7];
                float oz = T[i][8] * vx[i] + T[i][9] * vy[i] + T[i][10] * vz[i] + T[i][11];
                float* o = verts + (size_t)b * (NV * 3) + (vbase + i * 256 + t) * 3;
                o[0] = ox; o[1] = oy; o[2] = oz;
            }
        }
    }
}

// grid = nbg*2. Even blocks: 1024 verts (VPT=4). Odd blocks: 60-vert tail + joints.
__global__ __launch_bounds__(256) void verts_joints_kernel(
    const float* __restrict__ wsA, const float* __restrict__ Mbuf,
    const float* __restrict__ wts, const float* __restrict__ vtpl,
    float* __restrict__ verts, float* __restrict__ jout) {
    __shared__ float sA[BPB * 192];
    __shared__ float sM[1344];
    int bid = blockIdx.x;
    int bg = bid >> 1, chunk = bid & 1;
    int t = threadIdx.x;
    const float* src = wsA + (size_t)bg * (BPB * 192);
    for (int q = t; q < BPB * 192; q += 256) sA[q] = src[q];
    if (chunk) {
        for (int q = t; q < 1344; q += 256) sM[q] = Mbuf[q];
    }
    __syncthreads();

    if (chunk == 0) {
        blend_verts<4>(sA, wts, vtpl, verts, bg, 0, t);
    } else {
        blend_verts<1>(sA, wts, vtpl, verts, bg, 1024, t);
        // joints: jout[b, j, c] = sum_k sum_d M[j][k][d] * A[b][k][c*4+d]
        for (int o = t; o < BPB * 63; o += 256) {
            int bl = o / 63;
            int rem = o - bl * 63;
            int j = rem / 3;
            int c = rem - j * 3;
            const float* A = &sA[bl * 192 + c * 4];
            const float* Mj = &sM[j * 64];
            float acc = 0.f;
#pragma unroll
            for (int k = 0; k < 16; ++k) {
                float4 a = *(const float4*)&A[k * 12];
                float4 m = *(const float4*)&Mj[k * 4];
                acc += a.x * m.x + a.y * m.y + a.z * m.z + a.w * m.w;
            }
            jout[(size_t)(bg * BPB + bl) * 63 + rem] = acc;
        }
    }
}

extern "C" void kernel_launch(void* const* d_in, const int* in_sizes, int n_in,
                              void* d_out, int out_size, void* d_ws, size_t ws_size,
                              hipStream_t stream) {
    const float* theta = (const float*)d_in[1];
    const float* wrist = (const float*)d_in[2];
    const float* vtpl  = (const float*)d_in[3];
    const float* jreg  = (const float*)d_in[4];
    const float* hc    = (const float*)d_in[5];
    const float* hm    = (const float*)d_in[6];
    const float* wts   = (const float*)d_in[7];
    int B = in_sizes[1] / 45;  // 4096

    float* ws    = (float*)d_ws;
    float* wsA   = ws;                     // B*192
    float* Mbuf  = ws + (size_t)B * 192;   // 1344
    float* jt    = Mbuf + 1344;            // 48
    float* euler = jt + 48;                // B*45
    float* verts = (float*)d_out;
    float* jout  = verts + (size_t)B * NV * 3;

    hipMemsetAsync(Mbuf, 0, (1344 + 48) * sizeof(float), stream);
    precompute_kernel<<<64, 384, 0, stream>>>(vtpl, jreg, wts, Mbuf, jt);
    euler_kernel<<<(B * 45 + 255) / 256, 256, 0, stream>>>(theta, hc, hm, euler, B * 45);
    fk_kernel<<<B / 64, 64, 0, stream>>>(wrist, euler, jt, wsA);
    verts_joints_kernel<<<(B / BPB) * 2, 256, 0, stream>>>(wsA, Mbuf, wts, vtpl, verts, jout);
}

// Round 4
// 72.859 us; speedup vs baseline: 2.6652x; 1.6555x over previous
//
#include <hip/hip_runtime.h>

#define NV 1084
#define NB 8   // batches per verts block

// ws layout (floats):
//  [0, B*192)         A_rel [B][16][12]
//  [B*192, +1344)     M     [21][16][4]
//  next 48            Jt    [16][3]
//  next B*45          euler_pose [B][45]

__device__ inline void rodrigues9(float x, float y, float z, float R[9]) {
    float n2 = x * x + y * y + z * z + 1e-8f;
    float angle = sqrtf(n2);
    float inv = 1.0f / angle;
    float ax = x * inv, ay = y * inv, az = z * inv;
    float c = cosf(angle), s = sinf(angle);
    float C = 1.0f - c;
    R[0] = 1.0f - C * (ay * ay + az * az);
    R[1] = -s * az + C * ax * ay;
    R[2] = s * ay + C * ax * az;
    R[3] = s * az + C * ax * ay;
    R[4] = 1.0f - C * (ax * ax + az * az);
    R[5] = -s * ax + C * ay * az;
    R[6] = -s * ay + C * ax * az;
    R[7] = s * ax + C * ay * az;
    R[8] = 1.0f - C * (ax * ax + ay * ay);
}

// Batch-independent reductions over vertices: M[21][16][4] and Jt[16][3].
__global__ __launch_bounds__(384) void precompute_kernel(
    const float* __restrict__ vt, const float* __restrict__ jreg,
    const float* __restrict__ wts, float* __restrict__ Mbuf, float* __restrict__ jt) {
    int t = threadIdx.x;
    int v0 = blockIdx.x * 17;
    int v1 = min(v0 + 17, NV);
    if (t < 336) {
        int j = t >> 4, k = t & 15;
        float m0 = 0.f, m1 = 0.f, m2 = 0.f, s = 0.f;
        for (int v = v0; v < v1; ++v) {
            float jw = jreg[v * 21 + j] * wts[v * 16 + k];
            m0 += jw * vt[v * 3 + 0];
            m1 += jw * vt[v * 3 + 1];
            m2 += jw * vt[v * 3 + 2];
            s += jw;
        }
        float* mp = Mbuf + (t << 2);
        atomicAdd(mp + 0, m0);
        atomicAdd(mp + 1, m1);
        atomicAdd(mp + 2, m2);
        atomicAdd(mp + 3, s);
    } else if (t < 336 + 48) {
        int o = t - 336;
        int j = o / 3, c = o % 3;  // j < 16
        float acc = 0.f;
        for (int v = v0; v < v1; ++v) acc += vt[v * 3 + c] * jreg[v * 21 + j];
        atomicAdd(&jt[o], acc);
    }
}

// euler_pose[b,col] = hm[col] + sum_k theta[b,k] * hc[k,col]
__global__ __launch_bounds__(256) void euler_kernel(
    const float* __restrict__ theta, const float* __restrict__ hc,
    const float* __restrict__ hm, float* __restrict__ out, int total) {
    int i = blockIdx.x * 256 + threadIdx.x;
    if (i >= total) return;
    int b = i / 45, col = i % 45;
    const float* th = theta + b * 45;
    float acc = hm[col];
#pragma unroll
    for (int k = 0; k < 45; ++k) acc += th[k] * hc[k * 45 + col];
    out[i] = acc;
}

// FK split per chain: thread = (batch, role r in 0..4). Role r computes chain r
// (joints 3r+1..3r+3); every role redundantly computes the root A0; role 0 writes it.
__global__ __launch_bounds__(256) void fk_kernel(
    const float* __restrict__ wrist, const float* __restrict__ euler,
    const float* __restrict__ jt, float* __restrict__ wsA, int total) {
    int idx = blockIdx.x * 256 + threadIdx.x;
    if (idx >= total) return;  // total = B*5
    int b = idx / 5, r = idx - b * 5;

    float R[9];
    rodrigues9(wrist[b * 3 + 0], wrist[b * 3 + 1], wrist[b * 3 + 2], R);
    float J0x = jt[0], J0y = jt[1], J0z = jt[2];
    float Ap[12];
    Ap[0] = R[0]; Ap[1] = R[1]; Ap[2] = R[2]; Ap[3] = J0x;
    Ap[4] = R[3]; Ap[5] = R[4]; Ap[6] = R[5]; Ap[7] = J0y;
    Ap[8] = R[6]; Ap[9] = R[7]; Ap[10] = R[8]; Ap[11] = J0z;
    float* out = wsA + (size_t)b * 192;
    if (r == 0) {
#pragma unroll
        for (int row = 0; row < 3; ++row) {
            out[row * 4 + 0] = Ap[row * 4 + 0];
            out[row * 4 + 1] = Ap[row * 4 + 1];
            out[row * 4 + 2] = Ap[row * 4 + 2];
            out[row * 4 + 3] = Ap[row * 4 + 3] -
                (Ap[row * 4 + 0] * J0x + Ap[row * 4 + 1] * J0y + Ap[row * 4 + 2] * J0z);
        }
    }
    float px = J0x, py = J0y, pz = J0z;
    const float* eb = euler + (size_t)b * 45 + 9 * r;
#pragma unroll
    for (int s = 0; s < 3; ++s) {
        int i = r * 3 + s + 1;
        rodrigues9(eb[3 * s + 0], eb[3 * s + 1], eb[3 * s + 2], R);
        float jx = jt[i * 3 + 0], jy = jt[i * 3 + 1], jz = jt[i * 3 + 2];
        float tx = jx - px, ty = jy - py, tz = jz - pz;
        float An[12];
#pragma unroll
        for (int row = 0; row < 3; ++row) {
            An[row * 4 + 0] = Ap[row * 4 + 0] * R[0] + Ap[row * 4 + 1] * R[3] + Ap[row * 4 + 2] * R[6];
            An[row * 4 + 1] = Ap[row * 4 + 0] * R[1] + Ap[row * 4 + 1] * R[4] + Ap[row * 4 + 2] * R[7];
            An[row * 4 + 2] = Ap[row * 4 + 0] * R[2] + Ap[row * 4 + 1] * R[5] + Ap[row * 4 + 2] * R[8];
            An[row * 4 + 3] = Ap[row * 4 + 3] + Ap[row * 4 + 0] * tx + Ap[row * 4 + 1] * ty + Ap[row * 4 + 2] * tz;
        }
        float* oi = out + i * 12;
#pragma unroll
        for (int row = 0; row < 3; ++row) {
            oi[row * 4 + 0] = An[row * 4 + 0];
            oi[row * 4 + 1] = An[row * 4 + 1];
            oi[row * 4 + 2] = An[row * 4 + 2];
            oi[row * 4 + 3] = An[row * 4 + 3] -
                (An[row * 4 + 0] * jx + An[row * 4 + 1] * jy + An[row * 4 + 2] * jz);
        }
#pragma unroll
        for (int q = 0; q < 12; ++q) Ap[q] = An[q];
        px = jx; py = jy; pz = jz;
    }
}

// grid = (B/NB) * 6. chunk 0..4: 256 verts each (chunk 4 partial). chunk 5: joints.
// A is wave-uniform -> compiler emits s_load into SGPRs; no LDS anywhere.
__global__ __launch_bounds__(256, 6) void verts_joints_kernel(
    const float* __restrict__ wsA, const float* __restrict__ Mbuf,
    const float* __restrict__ wts, const float* __restrict__ vtpl,
    float* __restrict__ verts, float* __restrict__ jout) {
    int bid = blockIdx.x;
    int bg = bid / 6, chunk = bid - bg * 6;
    int t = threadIdx.x;
    int b0 = bg * NB;

    if (chunk < 5) {
        int v = chunk * 256 + t;
        bool valid = (v < NV);
        float w[16];
        float vx = 0.f, vy = 0.f, vz = 0.f;
        if (valid) {
            const float4* wp = (const float4*)&wts[v * 16];
            float4 q0 = wp[0], q1 = wp[1], q2 = wp[2], q3 = wp[3];
            w[0] = q0.x; w[1] = q0.y; w[2] = q0.z; w[3] = q0.w;
            w[4] = q1.x; w[5] = q1.y; w[6] = q1.z; w[7] = q1.w;
            w[8] = q2.x; w[9] = q2.y; w[10] = q2.z; w[11] = q2.w;
            w[12] = q3.x; w[13] = q3.y; w[14] = q3.z; w[15] = q3.w;
            vx = vtpl[v * 3 + 0]; vy = vtpl[v * 3 + 1]; vz = vtpl[v * 3 + 2];
        } else {
#pragma unroll
            for (int q = 0; q < 16; ++q) w[q] = 0.f;
        }
#pragma unroll 1
        for (int bb = 0; bb < NB; ++bb) {
            const float* A = wsA + (size_t)(b0 + bb) * 192;  // uniform -> SGPR loads
            float T[12];
#pragma unroll
            for (int q = 0; q < 12; ++q) T[q] = w[0] * A[q];
#pragma unroll
            for (int k = 1; k < 16; ++k) {
                float wk = w[k];
#pragma unroll
                for (int q = 0; q < 12; ++q) T[q] += wk * A[k * 12 + q];
            }
            if (valid) {
                float ox = T[0] * vx + T[1] * vy + T[2] * vz + T[3];
                float oy = T[4] * vx + T[5] * vy + T[6] * vz + T[7];
                float oz = T[8] * vx + T[9] * vy + T[10] * vz + T[11];
                float* o = verts + (size_t)(b0 + bb) * (NV * 3) + v * 3;
                o[0] = ox; o[1] = oy; o[2] = oz;
            }
        }
    } else {
        // joints: jout[b, j, c] = sum_k sum_d M[j][k][d] * A[b][k][c*4+d]
        for (int o = t; o < NB * 63; o += 256) {
            int bl = o / 63;
            int rem = o - bl * 63;
            int j = rem / 3;
            int c = rem - j * 3;
            const float* A = wsA + (size_t)(b0 + bl) * 192 + c * 4;
            const float* Mj = Mbuf + j * 64;
            float acc = 0.f;
#pragma unroll
            for (int k = 0; k < 16; ++k) {
                float4 a = *(const float4*)&A[k * 12];
                float4 m = *(const float4*)&Mj[k * 4];
                acc += a.x * m.x + a.y * m.y + a.z * m.z + a.w * m.w;
            }
            jout[(size_t)(b0 + bl) * 63 + rem] = acc;
        }
    }
}

extern "C" void kernel_launch(void* const* d_in, const int* in_sizes, int n_in,
                              void* d_out, int out_size, void* d_ws, size_t ws_size,
                              hipStream_t stream) {
    const float* theta = (const float*)d_in[1];
    const float* wrist = (const float*)d_in[2];
    const float* vtpl  = (const float*)d_in[3];
    const float* jreg  = (const float*)d_in[4];
    const float* hc    = (const float*)d_in[5];
    const float* hm    = (const float*)d_in[6];
    const float* wts   = (const float*)d_in[7];
    int B = in_sizes[1] / 45;  // 4096

    float* ws    = (float*)d_ws;
    float* wsA   = ws;                     // B*192
    float* Mbuf  = ws + (size_t)B * 192;   // 1344
    float* jt    = Mbuf + 1344;            // 48
    float* euler = jt + 48;                // B*45
    float* verts = (float*)d_out;
    float* jout  = verts + (size_t)B * NV * 3;

    hipMemsetAsync(Mbuf, 0, (1344 + 48) * sizeof(float), stream);
    precompute_kernel<<<64, 384, 0, stream>>>(vtpl, jreg, wts, Mbuf, jt);
    euler_kernel<<<(B * 45 + 255) / 256, 256, 0, stream>>>(theta, hc, hm, euler, B * 45);
    fk_kernel<<<(B * 5 + 255) / 256, 256, 0, stream>>>(wrist, euler, jt, wsA, B * 5);
    verts_joints_kernel<<<(B / NB) * 6, 256, 0, stream>>>(wsA, Mbuf, wts, vtpl, verts, jout);
}